// Round 1
// baseline (1146.207 us; speedup 1.0000x reference)
//
#include <hip/hip_runtime.h>
#include <stdint.h>
#include <stdio.h>

#define NOUT 512
#define NSEG 1024

typedef unsigned short u16;
typedef __attribute__((ext_vector_type(4))) float f32x4;
typedef __attribute__((ext_vector_type(8))) short s16x8;
typedef __attribute__((ext_vector_type(4))) unsigned short u16x4;

__device__ __forceinline__ u16 f2b(float f) {
  union { float f; uint32_t u; } v; v.f = f;
  uint32_t r = v.u + 0x7FFFu + ((v.u >> 16) & 1u);
  return (u16)(r >> 16);
}
__device__ __forceinline__ float b2f(u16 b) {
  union { uint32_t u; float f; } v; v.u = ((uint32_t)b) << 16;
  return v.f;
}

typedef __attribute__((address_space(1))) const void GAS;
typedef __attribute__((address_space(3))) void LAS;
__device__ __forceinline__ void llds16(const void* g, void* l) {
  __builtin_amdgcn_global_load_lds((GAS*)g, (LAS*)l, 16, 0, 0);
}

// ---------------- cast kernels ----------------
__global__ void k_cast(const float* __restrict__ src, u16* __restrict__ dst, long n4) {
  long i = blockIdx.x * (long)blockDim.x + threadIdx.x;
  long stride = (long)gridDim.x * blockDim.x;
  for (; i < n4; i += stride) {
    float4 v = reinterpret_cast<const float4*>(src)[i];
    u16x4 o;
    o.x = f2b(v.x); o.y = f2b(v.y); o.z = f2b(v.z); o.w = f2b(v.w);
    reinterpret_cast<u16x4*>(dst)[i] = o;
  }
}

// w: [K][512] f32 row-major -> out: [512][K] bf16 row-major (B^T for GEMM)
__global__ void k_wtcast(const float* __restrict__ w, u16* __restrict__ out, int K) {
  long total = (long)K * NOUT;
  long i = blockIdx.x * (long)blockDim.x + threadIdx.x;
  long stride = (long)gridDim.x * blockDim.x;
  for (; i < total; i += stride) {
    int c = (int)(i / K), k = (int)(i % K);
    out[i] = f2b(w[(long)k * NOUT + c]);
  }
}

// ---------------- segment sort ----------------
__global__ void k_hist(const int* __restrict__ ele, int* __restrict__ cnt, int N) {
  int i = blockIdx.x * blockDim.x + threadIdx.x;
  int stride = gridDim.x * blockDim.x;
  for (; i < N; i += stride) atomicAdd(&cnt[ele[i]], 1);
}

__global__ void k_scan(const int* __restrict__ cnt, int* __restrict__ off) {
  __shared__ int tmp[NSEG];
  int t = threadIdx.x;
  tmp[t] = cnt[t];
  __syncthreads();
  for (int o = 1; o < NSEG; o <<= 1) {
    int add = (t >= o) ? tmp[t - o] : 0;
    __syncthreads();
    tmp[t] += add;
    __syncthreads();
  }
  off[t] = tmp[t] - cnt[t];  // exclusive
}

__global__ void k_scatter(const int* __restrict__ ele, const int* __restrict__ off,
                          int* __restrict__ fill, int* __restrict__ rows, int N) {
  int i = blockIdx.x * blockDim.x + threadIdx.x;
  int stride = gridDim.x * blockDim.x;
  for (; i < N; i += stride) {
    int e = ele[i];
    int p = atomicAdd(&fill[e], 1);
    rows[off[e] + p] = i;
  }
}

// ---------------- BN stats / apply ----------------
__global__ void k_stats(const u16* __restrict__ hp, float* __restrict__ sum,
                        float* __restrict__ sumsq, int M) {
  int t = threadIdx.x;  // 256 threads -> cols 2t, 2t+1
  float s0 = 0, s1 = 0, q0 = 0, q1 = 0;
  for (int r = blockIdx.x; r < M; r += gridDim.x) {
    uint32_t v = *reinterpret_cast<const uint32_t*>(&hp[(long)r * NOUT + 2 * t]);
    float a = b2f((u16)(v & 0xffff)), b = b2f((u16)(v >> 16));
    s0 += a; q0 += a * a; s1 += b; q1 += b * b;
  }
  atomicAdd(&sum[2 * t], s0);
  atomicAdd(&sum[2 * t + 1], s1);
  atomicAdd(&sumsq[2 * t], q0);
  atomicAdd(&sumsq[2 * t + 1], q1);
}

__global__ void k_finalize(const float* __restrict__ sum, const float* __restrict__ sumsq,
                           const float* __restrict__ g, const float* __restrict__ be,
                           float* __restrict__ A, float* __restrict__ C, int M) {
  int c = threadIdx.x;  // 512
  float m = sum[c] / (float)M;
  float v = sumsq[c] / (float)M - m * m;
  float a = g[c] * rsqrtf(v + 1e-5f);
  A[c] = a;
  C[c] = be[c] - a * m;
}

__global__ void k_bnapply(const u16* __restrict__ hp, u16* __restrict__ h,
                          const float* __restrict__ A, const float* __restrict__ C, long n4) {
  long i = blockIdx.x * (long)blockDim.x + threadIdx.x;
  long stride = (long)gridDim.x * blockDim.x;
  for (; i < n4; i += stride) {
    u16x4 v = reinterpret_cast<const u16x4*>(hp)[i];
    int c0 = (int)((i * 4) & (NOUT - 1));
    float4 a = *reinterpret_cast<const float4*>(&A[c0]);
    float4 c = *reinterpret_cast<const float4*>(&C[c0]);
    u16x4 o;
    o.x = f2b(fmaxf(a.x * b2f(v.x) + c.x, 0.f));
    o.y = f2b(fmaxf(a.y * b2f(v.y) + c.y, 0.f));
    o.z = f2b(fmaxf(a.z * b2f(v.z) + c.z, 0.f));
    o.w = f2b(fmaxf(a.w * b2f(v.w) + c.w, 0.f));
    reinterpret_cast<u16x4*>(h)[i] = o;
  }
}

__global__ void k_final(const u16* __restrict__ hp, float* __restrict__ out,
                        const float* __restrict__ A, const float* __restrict__ C, long n4) {
  long i = blockIdx.x * (long)blockDim.x + threadIdx.x;
  long stride = (long)gridDim.x * blockDim.x;
  for (; i < n4; i += stride) {
    u16x4 v = reinterpret_cast<const u16x4*>(hp)[i];
    int c0 = (int)((i * 4) & (NOUT - 1));
    float4 a = *reinterpret_cast<const float4*>(&A[c0]);
    float4 c = *reinterpret_cast<const float4*>(&C[c0]);
    float4 o;
    o.x = fmaxf(a.x * b2f(v.x) + c.x, 0.f);
    o.y = fmaxf(a.y * b2f(v.y) + c.y, 0.f);
    o.z = fmaxf(a.z * b2f(v.z) + c.z, 0.f);
    o.w = fmaxf(a.w * b2f(v.w) + c.w, 0.f);
    reinterpret_cast<float4*>(out)[i] = o;
  }
}

// ---------------- segment mean ----------------
__global__ void k_segmean(const u16* __restrict__ h, u16* __restrict__ mean,
                          const int* __restrict__ off, const int* __restrict__ cnt,
                          const int* __restrict__ rows) {
  int s = blockIdx.x, t = threadIdx.x;  // 256 threads, cols 2t,2t+1
  int n = cnt[s], o = off[s];
  float s0 = 0, s1 = 0;
  for (int j = 0; j < n; ++j) {
    int r = rows[o + j];
    uint32_t v = *reinterpret_cast<const uint32_t*>(&h[(long)r * NOUT + 2 * t]);
    s0 += b2f((u16)(v & 0xffff));
    s1 += b2f((u16)(v >> 16));
  }
  float inv = 1.f / fmaxf((float)n, 1.f);
  uint32_t o2 = ((uint32_t)f2b(s1 * inv) << 16) | (uint32_t)f2b(s0 * inv);
  *reinterpret_cast<uint32_t*>(&mean[(long)s * NOUT + 2 * t]) = o2;
}

// ---------------- GEMM: C[M,512] = A[M,K](bf16, 3 source regions) @ W[K,512] ----------------
// wbt is W^T: [512][K] bf16 row-major. out is pre-BN result as bf16 (bias dropped: cancels in BN).
// Region r covers k in [start_r, e_r): source row = gather? ele[row] : row, width w_r.
__global__ __launch_bounds__(256, 2) void k_gemm(
    const u16* p0, const u16* p1, const u16* p2,
    int e0, int e1, int w0, int w1, int w2,
    int g0, int g1, int g2,
    const int* ele, const u16* __restrict__ wbt,
    u16* __restrict__ outp, int M, int K) {
  __shared__ __align__(16) u16 As[128 * 32];
  __shared__ __align__(16) u16 Bs[128 * 32];

  int nwg = gridDim.x;
  int bid = blockIdx.x;
  if ((nwg & 7) == 0) {              // XCD chunk swizzle (bijective when nwg%8==0)
    int chunk = nwg >> 3;
    bid = (bid & 7) * chunk + (bid >> 3);
  }
  int brow = (bid >> 2) * 128;       // col-tiles adjacent -> A-panel L2 reuse
  int bcol = (bid & 3) * 128;

  int tid = (int)threadIdx.x;
  int lane = tid & 63;
  int wv = tid >> 6;                 // 4 waves, 2x2
  int wr = wv >> 1, wc = wv & 1;
  int l4 = lane >> 2;                // 0..15 (staging row within 16-row group)
  int c8 = lane & 3;                 // staging col-octet

  int rr0 = brow + wv * 32 + l4;
  int r0 = rr0 < M ? rr0 : M - 1;
  int rr1 = rr0 + 16;
  int r1 = rr1 < M ? rr1 : M - 1;

  long off8 = (long)c8 * 8;
  const u16* a00 = p0 + (long)(g0 ? ele[r0] : r0) * w0 + off8;
  const u16* a01 = p1 + (long)(g1 ? ele[r0] : r0) * w1 + off8 - e0;
  const u16* a02 = p2 + (long)(g2 ? ele[r0] : r0) * w2 + off8 - e1;
  const u16* a10 = p0 + (long)(g0 ? ele[r1] : r1) * w0 + off8;
  const u16* a11 = p1 + (long)(g1 ? ele[r1] : r1) * w1 + off8 - e0;
  const u16* a12 = p2 + (long)(g2 ? ele[r1] : r1) * w2 + off8 - e1;
  int cb = bcol + wv * 32 + l4;      // < 512 always
  const u16* b0p = wbt + (long)cb * K + off8;
  const u16* b1p = b0p + (long)16 * K;

  u16* ldsA0 = &As[(wv * 2 + 0) * 512];
  u16* ldsA1 = &As[(wv * 2 + 1) * 512];
  u16* ldsB0 = &Bs[(wv * 2 + 0) * 512];
  u16* ldsB1 = &Bs[(wv * 2 + 1) * 512];

  f32x4 acc[4][4];
#pragma unroll
  for (int m = 0; m < 4; ++m)
#pragma unroll
    for (int n = 0; n < 4; ++n)
#pragma unroll
      for (int j = 0; j < 4; ++j) acc[m][n][j] = 0.f;

  int l15 = lane & 15, kg = lane >> 4;
  int KS = K >> 5;
  for (int ks = 0; ks < KS; ++ks) {
    int k0 = ks << 5;
    int rsel = (k0 >= e0) + (k0 >= e1);
    const u16* sa0 = rsel == 0 ? a00 : (rsel == 1 ? a01 : a02);
    const u16* sa1 = rsel == 0 ? a10 : (rsel == 1 ? a11 : a12);
    __syncthreads();
    llds16(sa0 + k0, ldsA0);
    llds16(sa1 + k0, ldsA1);
    llds16(b0p + k0, ldsB0);
    llds16(b1p + k0, ldsB1);
    __syncthreads();
    s16x8 af[4], bfv[4];
#pragma unroll
    for (int m = 0; m < 4; ++m)
      af[m] = *reinterpret_cast<const s16x8*>(&As[(wr * 64 + m * 16 + l15) * 32 + kg * 8]);
#pragma unroll
    for (int n = 0; n < 4; ++n)
      bfv[n] = *reinterpret_cast<const s16x8*>(&Bs[(wc * 64 + n * 16 + l15) * 32 + kg * 8]);
#pragma unroll
    for (int m = 0; m < 4; ++m)
#pragma unroll
      for (int n = 0; n < 4; ++n)
        acc[m][n] = __builtin_amdgcn_mfma_f32_16x16x32_bf16(af[m], bfv[n], acc[m][n], 0, 0, 0);
  }

  // C layout: col = lane&15, row = (lane>>4)*4 + j  [m89-verified]
#pragma unroll
  for (int m = 0; m < 4; ++m) {
    int row0 = brow + wr * 64 + m * 16 + kg * 4;
#pragma unroll
    for (int n = 0; n < 4; ++n) {
      int col = bcol + wc * 64 + n * 16 + l15;
#pragma unroll
      for (int j = 0; j < 4; ++j) {
        int rr = row0 + j;
        if (rr < M) outp[(long)rr * NOUT + col] = f2b(acc[m][n][j]);
      }
    }
  }
}

// ---------------- host ----------------
extern "C" void kernel_launch(void* const* d_in, const int* in_sizes, int n_in,
                              void* d_out, int out_size, void* d_ws, size_t ws_size,
                              hipStream_t stream) {
  const float* x    = (const float*)d_in[0];
  const float* dist = (const float*)d_in[1];
  const int* ele    = (const int*)d_in[3];
  const float* l1w  = (const float*)d_in[4];
  const float* l1g  = (const float*)d_in[6];
  const float* l1be = (const float*)d_in[7];
  const float* l2w  = (const float*)d_in[8];
  const float* l2g  = (const float*)d_in[10];
  const float* l2be = (const float*)d_in[11];
  const float* fw   = (const float*)d_in[12];
  const float* fg   = (const float*)d_in[14];
  const float* fbe  = (const float*)d_in[15];

  int N = in_sizes[0] / 1024;        // 100000
  float* out = (float*)d_out;
  u16* xbf = (u16*)d_out;            // x as bf16 [N][1024] overlays d_out (exact size match)

  char* w = (char*)d_ws;
  auto alloc = [&](size_t bytes) {
    char* p = w;
    w += (bytes + 255) & ~(size_t)255;
    return p;
  };
  u16* dist_bf = (u16*)alloc((size_t)N * 256 * 2);
  u16* hp      = (u16*)alloc((size_t)N * NOUT * 2);
  u16* h       = (u16*)alloc((size_t)N * NOUT * 2);
  u16* mean    = (u16*)alloc((size_t)NSEG * NOUT * 2);
  u16* w1bt    = (u16*)alloc((size_t)NOUT * 1280 * 2);
  u16* w2bt    = (u16*)alloc((size_t)NOUT * 1280 * 2);
  u16* fbt     = (u16*)alloc((size_t)NOUT * 1024 * 2);
  float* colsum  = (float*)alloc(NOUT * 4 * 2);  // sum + sumsq adjacent
  float* colsumsq = colsum + NOUT;
  float* bnA   = (float*)alloc(NOUT * 4);
  float* bnC   = (float*)alloc(NOUT * 4);
  int* seg_cnt = (int*)alloc(NSEG * 4);
  int* seg_off = (int*)alloc(NSEG * 4);
  int* seg_fill = (int*)alloc(NSEG * 4);
  int* rows    = (int*)alloc((size_t)N * 4);

  size_t need = (size_t)(w - (char*)d_ws);
  if (need > ws_size) {
    fprintf(stderr, "kernel_launch: ws too small: need %zu have %zu\n", need, ws_size);
    return;
  }

  long n4x = (long)N * 1024 / 4;
  long n4d = (long)N * 256 / 4;
  long n4h = (long)N * NOUT / 4;
  int panels = (N + 127) / 128;
  int gemmGrid = panels * 4;

  // casts
  k_cast<<<4096, 256, 0, stream>>>(x, xbf, n4x);
  k_cast<<<2048, 256, 0, stream>>>(dist, dist_bf, n4d);
  k_wtcast<<<1280, 256, 0, stream>>>(l1w, w1bt, 1280);
  k_wtcast<<<1280, 256, 0, stream>>>(l2w, w2bt, 1280);
  k_wtcast<<<1024, 256, 0, stream>>>(fw, fbt, 1024);

  // segment sort (shared by both layers)
  hipMemsetAsync(seg_cnt, 0, NSEG * 4, stream);
  hipMemsetAsync(seg_fill, 0, NSEG * 4, stream);
  k_hist<<<512, 256, 0, stream>>>(ele, seg_cnt, N);
  k_scan<<<1, NSEG, 0, stream>>>(seg_cnt, seg_off);
  k_scatter<<<512, 256, 0, stream>>>(ele, seg_off, seg_fill, rows, N);

  // ---- layer 1 ----
  k_gemm<<<gemmGrid, 256, 0, stream>>>(xbf, dist_bf, dist_bf, 1024, 1280, 1024, 256, 0,
                                       0, 0, 0, ele, w1bt, hp, N, 1280);
  hipMemsetAsync(colsum, 0, NOUT * 4 * 2, stream);
  k_stats<<<1024, 256, 0, stream>>>(hp, colsum, colsumsq, N);
  k_finalize<<<1, NOUT, 0, stream>>>(colsum, colsumsq, l1g, l1be, bnA, bnC, N);
  k_bnapply<<<4096, 256, 0, stream>>>(hp, h, bnA, bnC, n4h);
  k_segmean<<<NSEG, 256, 0, stream>>>(h, mean, seg_off, seg_cnt, rows);

  // ---- layer 2 ----
  k_gemm<<<gemmGrid, 256, 0, stream>>>(h, mean, dist_bf, 512, 1024, 512, 512, 256,
                                       0, 1, 0, ele, w2bt, hp, N, 1280);
  hipMemsetAsync(colsum, 0, NOUT * 4 * 2, stream);
  k_stats<<<1024, 256, 0, stream>>>(hp, colsum, colsumsq, N);
  k_finalize<<<1, NOUT, 0, stream>>>(colsum, colsumsq, l2g, l2be, bnA, bnC, N);
  k_bnapply<<<4096, 256, 0, stream>>>(hp, h, bnA, bnC, n4h);
  k_segmean<<<NSEG, 256, 0, stream>>>(h, mean, seg_off, seg_cnt, rows);

  // ---- final layer ----
  k_gemm<<<gemmGrid, 256, 0, stream>>>(h, mean, mean, 512, 1024, 512, 512, 0,
                                       0, 1, 0, ele, fbt, hp, N, 1024);
  hipMemsetAsync(colsum, 0, NOUT * 4 * 2, stream);
  k_stats<<<1024, 256, 0, stream>>>(hp, colsum, colsumsq, N);
  k_finalize<<<1, NOUT, 0, stream>>>(colsum, colsumsq, fg, fbe, bnA, bnC, N);
  k_final<<<4096, 256, 0, stream>>>(hp, out, bnA, bnC, n4h);
}